// Round 1
// baseline (172.676 us; speedup 1.0000x reference)
//
#include <hip/hip_runtime.h>

#define S_INV (1.0f / 7.0f)
#define COORD_W 5.0f
#define NOOBJ_W 0.5f

__global__ __launch_bounds__(256) void yolo_loss_kernel(
    const float* __restrict__ outp, const float* __restrict__ tgtp,
    float* __restrict__ ws, int ncells)
{
    int tid = blockIdx.x * blockDim.x + threadIdx.x;
    int stride = gridDim.x * blockDim.x;

    float acc_total = 0.f, acc_iou = 0.f, acc_acc = 0.f;

    for (int cell = tid; cell < ncells; cell += stride) {
        const float* o = outp + (size_t)cell * 30;
        const float* t = tgtp + (size_t)cell * 30;

        float ov[30], tv[30];
#pragma unroll
        for (int i = 0; i < 15; ++i) {
            float2 a = *reinterpret_cast<const float2*>(o + 2 * i);
            float2 b = *reinterpret_cast<const float2*>(t + 2 * i);
            ov[2 * i] = a.x; ov[2 * i + 1] = a.y;
            tv[2 * i] = b.x; tv[2 * i + 1] = b.y;
        }

        float w_obj = (tv[4] > 0.f) ? 1.f : 0.f;
        float w_no = 1.f - w_obj;

        // ---- class loss + argmax accuracy (first-max tie-break) ----
        float cls = 0.f;
        float omax = ov[10]; int oarg = 0;
        float tmax = tv[10]; int targ = 0;
#pragma unroll
        for (int c = 0; c < 20; ++c) {
            float d = ov[10 + c] - tv[10 + c];
            cls += d * d;
            if (ov[10 + c] > omax) { omax = ov[10 + c]; oarg = c; }
            if (tv[10 + c] > tmax) { tmax = tv[10 + c]; targ = c; }
        }

        // ---- IOU of both predicted boxes vs target box 0 ----
        float t_x = tv[0] * S_INV, t_y = tv[1] * S_INV;
        float t_w = tv[2], t_h = tv[3];
        float t_l = t_x - 0.5f * t_w, t_r = t_x + 0.5f * t_w;
        float t_t = t_y - 0.5f * t_h, t_b = t_y + 0.5f * t_h;
        float area_t = t_w * t_h;

        float iou0, iou1;
        {
            float x = ov[0] * S_INV, y = ov[1] * S_INV;
            float w = ov[2], h = ov[3];
            float l = x - 0.5f * w, r = x + 0.5f * w;
            float tt = y - 0.5f * h, bb = y + 0.5f * h;
            float iw = fmaxf(fminf(r, t_r) - fmaxf(l, t_l), 0.f);
            float ih = fmaxf(fminf(bb, t_b) - fmaxf(tt, t_t), 0.f);
            float inter = iw * ih;
            iou0 = inter / (w * h + area_t - inter);
        }
        {
            float x = ov[5] * S_INV, y = ov[6] * S_INV;
            float w = ov[7], h = ov[8];
            float l = x - 0.5f * w, r = x + 0.5f * w;
            float tt = y - 0.5f * h, bb = y + 0.5f * h;
            float iw = fmaxf(fminf(r, t_r) - fmaxf(l, t_l), 0.f);
            float ih = fmaxf(fminf(bb, t_b) - fmaxf(tt, t_t), 0.f);
            float inter = iw * ih;
            iou1 = inter / (w * h + area_t - inter);
        }

        // resp = argmax(iou) with first-max tie-break
        bool r1 = (iou1 > iou0);
        float max_iou = r1 ? iou1 : iou0;

        // runtime selects (v_cndmask), NO runtime array indexing (rule #20)
        float os0 = r1 ? ov[5] : ov[0];
        float os1 = r1 ? ov[6] : ov[1];
        float os2 = r1 ? ov[7] : ov[2];
        float os3 = r1 ? ov[8] : ov[3];
        float os4 = r1 ? ov[9] : ov[4];
        float ts0 = r1 ? tv[5] : tv[0];
        float ts1 = r1 ? tv[6] : tv[1];
        float ts2 = r1 ? tv[7] : tv[2];
        float ts3 = r1 ? tv[8] : tv[3];
        float oa4 = r1 ? ov[4] : ov[9];   // abandoned box conf

        float d0 = os0 - ts0, d1 = os1 - ts1;
        float d2 = sqrtf(os2) - sqrtf(ts2);
        float d3 = sqrtf(os3) - sqrtf(ts3);
        float coord = d0 * d0 + d1 * d1 + d2 * d2 + d3 * d3;

        float dc = os4 - max_iou;
        float conf = dc * dc;
        float aband = oa4 * oa4;
        float n0 = ov[4] - tv[4], n1 = ov[9] - tv[9];
        float noobj = n0 * n0 + n1 * n1;

        float cell_total = w_obj * (COORD_W * coord + conf + NOOBJ_W * aband + cls)
                         + NOOBJ_W * w_no * noobj;

        acc_total += cell_total;
        acc_iou   += w_obj * max_iou;
        acc_acc   += w_obj * ((oarg == targ) ? 1.f : 0.f);
    }

    // ---- block reduction: wave64 shuffle, then LDS across 4 waves ----
#pragma unroll
    for (int off = 32; off > 0; off >>= 1) {
        acc_total += __shfl_down(acc_total, off);
        acc_iou   += __shfl_down(acc_iou, off);
        acc_acc   += __shfl_down(acc_acc, off);
    }
    __shared__ float s[3][4];
    int wave = threadIdx.x >> 6;
    int lane = threadIdx.x & 63;
    if (lane == 0) { s[0][wave] = acc_total; s[1][wave] = acc_iou; s[2][wave] = acc_acc; }
    __syncthreads();
    if (threadIdx.x == 0) {
        float t0 = 0.f, t1 = 0.f, t2 = 0.f;
#pragma unroll
        for (int w = 0; w < 4; ++w) { t0 += s[0][w]; t1 += s[1][w]; t2 += s[2][w]; }
        ws[blockIdx.x * 3 + 0] = t0;
        ws[blockIdx.x * 3 + 1] = t1;
        ws[blockIdx.x * 3 + 2] = t2;
    }
}

__global__ __launch_bounds__(256) void yolo_reduce_kernel(
    const float* __restrict__ ws, float* __restrict__ out, int nblocks)
{
    float t0 = 0.f, t1 = 0.f, t2 = 0.f;
    for (int i = threadIdx.x; i < nblocks; i += blockDim.x) {
        t0 += ws[i * 3 + 0];
        t1 += ws[i * 3 + 1];
        t2 += ws[i * 3 + 2];
    }
#pragma unroll
    for (int off = 32; off > 0; off >>= 1) {
        t0 += __shfl_down(t0, off);
        t1 += __shfl_down(t1, off);
        t2 += __shfl_down(t2, off);
    }
    __shared__ float s[3][4];
    int wave = threadIdx.x >> 6;
    int lane = threadIdx.x & 63;
    if (lane == 0) { s[0][wave] = t0; s[1][wave] = t1; s[2][wave] = t2; }
    __syncthreads();
    if (threadIdx.x == 0) {
        float a0 = 0.f, a1 = 0.f, a2 = 0.f;
#pragma unroll
        for (int w = 0; w < 4; ++w) { a0 += s[0][w]; a1 += s[1][w]; a2 += s[2][w]; }
        out[0] = a0;  // total
        out[1] = a1;  // sum_iou
        out[2] = a2;  // accurate_num
    }
}

extern "C" void kernel_launch(void* const* d_in, const int* in_sizes, int n_in,
                              void* d_out, int out_size, void* d_ws, size_t ws_size,
                              hipStream_t stream) {
    const float* outp = (const float*)d_in[0];
    const float* tgtp = (const float*)d_in[1];
    float* ws = (float*)d_ws;
    float* o = (float*)d_out;

    const int ncells = in_sizes[0] / 30;   // 32768*7*7 = 1,605,632
    const int blocks = 2048;

    yolo_loss_kernel<<<blocks, 256, 0, stream>>>(outp, tgtp, ws, ncells);
    yolo_reduce_kernel<<<1, 256, 0, stream>>>(ws, o, blocks);
}

// Round 2
// 76.854 us; speedup vs baseline: 2.2468x; 2.2468x over previous
//
#include <hip/hip_runtime.h>

#define S_INV (1.0f / 7.0f)
#define COORD_W 5.0f
#define NOOBJ_W 0.5f

#define CHUNK 256          // cells per block-chunk
#define PAD 34             // padded LDS stride in floats (136 B: 8-aligned, 2-way bank alias = free)

__global__ __launch_bounds__(256) void yolo_loss_kernel(
    const float* __restrict__ outp, const float* __restrict__ tgtp,
    float* __restrict__ ws, int ncells)
{
    __shared__ float so[CHUNK * PAD];
    __shared__ float st[CHUNK * PAD];

    const int t = threadIdx.x;
    float acc_total = 0.f, acc_iou = 0.f, acc_acc = 0.f;

    const int nchunks = ncells / CHUNK;   // 6272, exact
    for (int chunk = blockIdx.x; chunk < nchunks; chunk += gridDim.x) {
        const size_t base = (size_t)chunk * CHUNK * 30;
        const float* ob = outp + base;
        const float* tb = tgtp + base;

        __syncthreads();   // previous chunk's readers done before overwrite

        // ---- coalesced staging: 3840 float4 = 15 rounds x 256 threads ----
        // rounds 0..6 pure 'out', round 7 mixed, 8..14 pure 'tgt'
#pragma unroll
        for (int r = 0; r < 15; ++r) {
            int idx = r * 256 + t;                 // 0..3839
            bool is_o = idx < 1920;
            int li = is_o ? idx : idx - 1920;      // float4 index within array chunk
            const float* src = (is_o ? ob : tb) + li * 4;
            float4 v = *reinterpret_cast<const float4*>(src);
            float* dst = is_o ? so : st;
            int e0 = li * 4;
            int cell = (int)((unsigned)e0 / 30u);  // magic-mul
            int off  = e0 - cell * 30;
            dst[cell * PAD + off] = v.x;
            int o1 = off + 1, c1 = cell; if (o1 >= 30) { o1 -= 30; ++c1; }
            dst[c1 * PAD + o1] = v.y;
            int o2 = off + 2, c2 = cell; if (o2 >= 30) { o2 -= 30; ++c2; }
            dst[c2 * PAD + o2] = v.z;
            int o3 = off + 3, c3 = cell; if (o3 >= 30) { o3 -= 30; ++c3; }
            dst[c3 * PAD + o3] = v.w;
        }
        __syncthreads();

        // ---- per-cell compute from LDS (thread t owns local cell t) ----
        float ov[30], tv[30];
#pragma unroll
        for (int i = 0; i < 15; ++i) {
            float2 a = *reinterpret_cast<const float2*>(&so[t * PAD + 2 * i]);
            float2 b = *reinterpret_cast<const float2*>(&st[t * PAD + 2 * i]);
            ov[2 * i] = a.x; ov[2 * i + 1] = a.y;
            tv[2 * i] = b.x; tv[2 * i + 1] = b.y;
        }

        float w_obj = (tv[4] > 0.f) ? 1.f : 0.f;
        float w_no = 1.f - w_obj;

        // class loss + argmax accuracy (first-max tie-break)
        float cls = 0.f;
        float omax = ov[10]; int oarg = 0;
        float tmax = tv[10]; int targ = 0;
#pragma unroll
        for (int c = 0; c < 20; ++c) {
            float d = ov[10 + c] - tv[10 + c];
            cls += d * d;
            if (ov[10 + c] > omax) { omax = ov[10 + c]; oarg = c; }
            if (tv[10 + c] > tmax) { tmax = tv[10 + c]; targ = c; }
        }

        // IOU of both predicted boxes vs target box 0
        float t_x = tv[0] * S_INV, t_y = tv[1] * S_INV;
        float t_w = tv[2], t_h = tv[3];
        float t_l = t_x - 0.5f * t_w, t_r = t_x + 0.5f * t_w;
        float t_t = t_y - 0.5f * t_h, t_b = t_y + 0.5f * t_h;
        float area_t = t_w * t_h;

        float iou0, iou1;
        {
            float x = ov[0] * S_INV, y = ov[1] * S_INV;
            float w = ov[2], h = ov[3];
            float l = x - 0.5f * w, r = x + 0.5f * w;
            float tt = y - 0.5f * h, bb = y + 0.5f * h;
            float iw = fmaxf(fminf(r, t_r) - fmaxf(l, t_l), 0.f);
            float ih = fmaxf(fminf(bb, t_b) - fmaxf(tt, t_t), 0.f);
            float inter = iw * ih;
            iou0 = inter / (w * h + area_t - inter);
        }
        {
            float x = ov[5] * S_INV, y = ov[6] * S_INV;
            float w = ov[7], h = ov[8];
            float l = x - 0.5f * w, r = x + 0.5f * w;
            float tt = y - 0.5f * h, bb = y + 0.5f * h;
            float iw = fmaxf(fminf(r, t_r) - fmaxf(l, t_l), 0.f);
            float ih = fmaxf(fminf(bb, t_b) - fmaxf(tt, t_t), 0.f);
            float inter = iw * ih;
            iou1 = inter / (w * h + area_t - inter);
        }

        bool r1 = (iou1 > iou0);
        float max_iou = r1 ? iou1 : iou0;

        float os0 = r1 ? ov[5] : ov[0];
        float os1 = r1 ? ov[6] : ov[1];
        float os2 = r1 ? ov[7] : ov[2];
        float os3 = r1 ? ov[8] : ov[3];
        float os4 = r1 ? ov[9] : ov[4];
        float ts0 = r1 ? tv[5] : tv[0];
        float ts1 = r1 ? tv[6] : tv[1];
        float ts2 = r1 ? tv[7] : tv[2];
        float ts3 = r1 ? tv[8] : tv[3];
        float oa4 = r1 ? ov[4] : ov[9];

        float d0 = os0 - ts0, d1 = os1 - ts1;
        float d2 = sqrtf(os2) - sqrtf(ts2);
        float d3 = sqrtf(os3) - sqrtf(ts3);
        float coord = d0 * d0 + d1 * d1 + d2 * d2 + d3 * d3;

        float dc = os4 - max_iou;
        float conf = dc * dc;
        float aband = oa4 * oa4;
        float n0 = ov[4] - tv[4], n1 = ov[9] - tv[9];
        float noobj = n0 * n0 + n1 * n1;

        float cell_total = w_obj * (COORD_W * coord + conf + NOOBJ_W * aband + cls)
                         + NOOBJ_W * w_no * noobj;

        acc_total += cell_total;
        acc_iou   += w_obj * max_iou;
        acc_acc   += w_obj * ((oarg == targ) ? 1.f : 0.f);
    }

    // ---- block reduction: wave64 shuffle, then LDS across 4 waves ----
#pragma unroll
    for (int off = 32; off > 0; off >>= 1) {
        acc_total += __shfl_down(acc_total, off);
        acc_iou   += __shfl_down(acc_iou, off);
        acc_acc   += __shfl_down(acc_acc, off);
    }
    __shared__ float s[3][4];
    int wave = threadIdx.x >> 6;
    int lane = threadIdx.x & 63;
    __syncthreads();   // LDS reuse safety (s overlaps nothing, but order vs chunk loop)
    if (lane == 0) { s[0][wave] = acc_total; s[1][wave] = acc_iou; s[2][wave] = acc_acc; }
    __syncthreads();
    if (threadIdx.x == 0) {
        float t0 = 0.f, t1 = 0.f, t2 = 0.f;
#pragma unroll
        for (int w = 0; w < 4; ++w) { t0 += s[0][w]; t1 += s[1][w]; t2 += s[2][w]; }
        ws[blockIdx.x * 3 + 0] = t0;
        ws[blockIdx.x * 3 + 1] = t1;
        ws[blockIdx.x * 3 + 2] = t2;
    }
}

__global__ __launch_bounds__(256) void yolo_reduce_kernel(
    const float* __restrict__ ws, float* __restrict__ out, int nblocks)
{
    float t0 = 0.f, t1 = 0.f, t2 = 0.f;
    for (int i = threadIdx.x; i < nblocks; i += blockDim.x) {
        t0 += ws[i * 3 + 0];
        t1 += ws[i * 3 + 1];
        t2 += ws[i * 3 + 2];
    }
#pragma unroll
    for (int off = 32; off > 0; off >>= 1) {
        t0 += __shfl_down(t0, off);
        t1 += __shfl_down(t1, off);
        t2 += __shfl_down(t2, off);
    }
    __shared__ float s[3][4];
    int wave = threadIdx.x >> 6;
    int lane = threadIdx.x & 63;
    if (lane == 0) { s[0][wave] = t0; s[1][wave] = t1; s[2][wave] = t2; }
    __syncthreads();
    if (threadIdx.x == 0) {
        float a0 = 0.f, a1 = 0.f, a2 = 0.f;
#pragma unroll
        for (int w = 0; w < 4; ++w) { a0 += s[0][w]; a1 += s[1][w]; a2 += s[2][w]; }
        out[0] = a0;
        out[1] = a1;
        out[2] = a2;
    }
}

extern "C" void kernel_launch(void* const* d_in, const int* in_sizes, int n_in,
                              void* d_out, int out_size, void* d_ws, size_t ws_size,
                              hipStream_t stream) {
    const float* outp = (const float*)d_in[0];
    const float* tgtp = (const float*)d_in[1];
    float* ws = (float*)d_ws;
    float* o = (float*)d_out;

    const int ncells = in_sizes[0] / 30;   // 32768*7*7 = 1,605,632
    const int blocks = 2048;

    yolo_loss_kernel<<<blocks, 256, 0, stream>>>(outp, tgtp, ws, ncells);
    yolo_reduce_kernel<<<1, 256, 0, stream>>>(ws, o, blocks);
}